// Round 3
// baseline (3969.584 us; speedup 1.0000x reference)
//
#include <hip/hip_runtime.h>
#include <hip/hip_bf16.h>
#include <stdint.h>
#include <stddef.h>

// Problem sizes (fixed)
#define HID   1024
#define NB    64
#define SEQ   512
#define G3    3072   // 3*HID
#define EMB   512
#define LAT   64

typedef __attribute__((ext_vector_type(4))) float f32x4;
typedef __attribute__((ext_vector_type(8))) short bfrag;  // 8 bf16 (4 VGPRs)

// ---------- helpers ----------
__device__ __forceinline__ unsigned short f2bf(float x) {   // RNE f32->bf16
  union { float f; unsigned u; } v; v.f = x;
  unsigned u = v.u + 0x7fffu + ((v.u >> 16) & 1u);
  return (unsigned short)(u >> 16);
}
__device__ __forceinline__ float bf2f(short s) {
  union { unsigned u; float f; } v; v.u = ((unsigned)(unsigned short)s) << 16;
  return v.f;
}
__device__ __forceinline__ float fsig(float x) {
  return 1.0f / (1.0f + __builtin_exp2f(-1.4426950408889634f * x));
}
__device__ __forceinline__ float ftanh(float x) {
  return 1.0f - 2.0f / (1.0f + __builtin_exp2f(2.8853900817779268f * x));
}
__device__ __forceinline__ void gload_lds16(const void* g, void* l) {
  __builtin_amdgcn_global_load_lds(
      (const __attribute__((address_space(1))) unsigned int*)g,
      (__attribute__((address_space(3))) unsigned int*)l, 16, 0, 0);
}

// ---------- kernel 0: w_ih f32 -> bf16 ----------
__global__ void cvt_wih_kernel(const float* __restrict__ in, short* __restrict__ out) {
  int i = (blockIdx.x * 256 + threadIdx.x) * 8;   // grid sized exactly
  f32x4 a = *(const f32x4*)(in + i);
  f32x4 b = *(const f32x4*)(in + i + 4);
  bfrag o;
  o[0]=(short)f2bf(a[0]); o[1]=(short)f2bf(a[1]); o[2]=(short)f2bf(a[2]); o[3]=(short)f2bf(a[3]);
  o[4]=(short)f2bf(b[0]); o[5]=(short)f2bf(b[1]); o[6]=(short)f2bf(b[2]); o[7]=(short)f2bf(b[3]);
  *(bfrag*)(out + i) = o;
}

// ---------- kernel 1: gx = emb[ids] @ w_ih^T  (bf16 MFMA, fp32 acc, bf16 out) ----------
// grid (24, 256): x = n-tile (3072/128), y = m-tile (32768/128). 256 threads (4 waves 2x2).
__global__ void __launch_bounds__(256) gemm_gx_kernel(
    const int* __restrict__ ids, const float* __restrict__ emb,
    const short* __restrict__ wih, short* __restrict__ gx)
{
  const int nt = blockIdx.x, mt = blockIdx.y;
  const int tid = threadIdx.x;
  const int lane = tid & 63, wave = tid >> 6;
  const int wr = wave >> 1, wc = wave & 1;

  __shared__ __align__(16) short A_lds[128 * 48];  // padded to 48 (16B-aligned rows)
  __shared__ __align__(16) short B_lds[128 * 32];
  __shared__ int ids_s[128];

  if (tid < 128) ids_s[tid] = ids[mt * 128 + tid];
  __syncthreads();

  f32x4 acc[4][4];
  #pragma unroll
  for (int i = 0; i < 4; ++i)
    #pragma unroll
    for (int j = 0; j < 4; ++j) acc[i][j] = (f32x4){0.f, 0.f, 0.f, 0.f};

  const int r_stage = tid >> 1;
  const int kh = (tid & 1) * 16;

  #pragma unroll 1
  for (int kc = 0; kc < 16; ++kc) {
    __syncthreads();   // protect LDS reuse
    // A stage: gather emb rows, cvt f32->bf16, ds_write
    {
      const float* src = emb + (size_t)ids_s[r_stage] * 512 + kc * 32 + kh;
      f32x4 v0 = *(const f32x4*)(src);
      f32x4 v1 = *(const f32x4*)(src + 4);
      f32x4 v2 = *(const f32x4*)(src + 8);
      f32x4 v3 = *(const f32x4*)(src + 12);
      bfrag p0, p1;
      p0[0]=(short)f2bf(v0[0]); p0[1]=(short)f2bf(v0[1]); p0[2]=(short)f2bf(v0[2]); p0[3]=(short)f2bf(v0[3]);
      p0[4]=(short)f2bf(v1[0]); p0[5]=(short)f2bf(v1[1]); p0[6]=(short)f2bf(v1[2]); p0[7]=(short)f2bf(v1[3]);
      p1[0]=(short)f2bf(v2[0]); p1[1]=(short)f2bf(v2[1]); p1[2]=(short)f2bf(v2[2]); p1[3]=(short)f2bf(v2[3]);
      p1[4]=(short)f2bf(v3[0]); p1[5]=(short)f2bf(v3[1]); p1[6]=(short)f2bf(v3[2]); p1[7]=(short)f2bf(v3[3]);
      *(bfrag*)&A_lds[r_stage * 48 + kh]     = p0;
      *(bfrag*)&A_lds[r_stage * 48 + kh + 8] = p1;
    }
    // B stage: direct global->LDS (bf16 already), 2 instrs per wave
    {
      #pragma unroll
      for (int ii = 0; ii < 2; ++ii) {
        int i = wave * 2 + ii;
        const short* src = wih + (size_t)(nt * 128 + i * 16 + (lane >> 2)) * 512
                               + kc * 32 + (lane & 3) * 8;
        gload_lds16((const void*)src, (void*)&B_lds[i * 512]);
      }
    }
    asm volatile("s_waitcnt vmcnt(0)" ::: "memory");
    __syncthreads();

    bfrag a[4], b[4];
    #pragma unroll
    for (int mi = 0; mi < 4; ++mi)
      a[mi] = *(const bfrag*)&A_lds[(wr * 64 + mi * 16 + (lane & 15)) * 48 + (lane >> 4) * 8];
    #pragma unroll
    for (int ni = 0; ni < 4; ++ni)
      b[ni] = *(const bfrag*)&B_lds[(wc * 64 + ni * 16 + (lane & 15)) * 32 + (lane >> 4) * 8];
    #pragma unroll
    for (int mi = 0; mi < 4; ++mi)
      #pragma unroll
      for (int ni = 0; ni < 4; ++ni)
        acc[mi][ni] = __builtin_amdgcn_mfma_f32_16x16x32_bf16(a[mi], b[ni], acc[mi][ni], 0, 0, 0);
  }

  // epilogue: store bf16 gx[m][n]
  #pragma unroll
  for (int mi = 0; mi < 4; ++mi)
    #pragma unroll
    for (int ni = 0; ni < 4; ++ni)
      #pragma unroll
      for (int r = 0; r < 4; ++r) {
        int m = mt * 128 + wr * 64 + mi * 16 + (lane >> 4) * 4 + r;
        int n = nt * 128 + wc * 64 + ni * 16 + (lane & 15);
        gx[(size_t)m * G3 + n] = (short)f2bf(acc[mi][ni][r]);
      }
}

// ---------- kernel 2: persistent GRU scan (PLAIN launch, 64 WGs <= 256 CUs) ----------
// team = blockIdx>>4 owns 16 batch rows; each wave owns 16 hidden cols x 3 gates
// (w_hh slice in ~384 VGPRs). Per step: stage team h (32KB, swizzled) to LDS,
// 96 MFMAs/wave, gates in fp32 regs, COHERENT (agent-scope) bf16 h_new stores,
// device-scope team barrier with explicit agent release/acquire fences.
__global__ void __launch_bounds__(256, 1) gru_scan_kernel(
    const short* __restrict__ gx, const float* __restrict__ whh,
    const float* __restrict__ bihp, const float* __restrict__ bhhp,
    short* __restrict__ hbuf, unsigned int* __restrict__ cnt,
    float* __restrict__ hsum)
{
  const int team = blockIdx.x >> 4;
  const int wgi  = blockIdx.x & 15;
  const int tid  = threadIdx.x;
  const int lane = tid & 63, wave = tid >> 6;
  const int jcol = (wgi * 4 + wave) * 16 + (lane & 15);  // hidden col this lane owns
  const int bsub = (lane >> 4) * 4;                      // local batch-row base (C/D rows)
  const int bteam = team * 16;

  __shared__ __align__(16) short h_lds[16 * 1024];       // 32 KB, swizzled layout

  // --- load w_hh slice into registers as B-fragments (bf16) ---
  bfrag wfrag[3][32];
  #pragma unroll
  for (int g = 0; g < 3; ++g) {
    const float* wrow = whh + (size_t)(g * 1024 + jcol) * 1024 + (lane >> 4) * 8;
    #pragma unroll
    for (int ks = 0; ks < 32; ++ks) {
      const float* p = wrow + ks * 32;
      f32x4 lo = *(const f32x4*)p;
      f32x4 hi = *(const f32x4*)(p + 4);
      bfrag f;
      f[0]=(short)f2bf(lo[0]); f[1]=(short)f2bf(lo[1]); f[2]=(short)f2bf(lo[2]); f[3]=(short)f2bf(lo[3]);
      f[4]=(short)f2bf(hi[0]); f[5]=(short)f2bf(hi[1]); f[6]=(short)f2bf(hi[2]); f[7]=(short)f2bf(hi[3]);
      wfrag[g][ks] = f;
    }
  }
  float bih_r[3], bhh_r[3];
  #pragma unroll
  for (int g = 0; g < 3; ++g) {
    bih_r[g] = bihp[g * 1024 + jcol];
    bhh_r[g] = bhhp[g * 1024 + jcol];
  }

  float hprev[4] = {0.f, 0.f, 0.f, 0.f};
  float hacc[4]  = {0.f, 0.f, 0.f, 0.f};
  unsigned int* mycnt = cnt + team * 64;   // 256B-separated counters
  const int bl = lane & 15;
  const int xorm = (bl & 7) << 4;
  const char* lbase = (const char*)h_lds + bl * 2048;

  #pragma unroll 1
  for (int s = 0; s < SEQ; ++s) {
    const short* hsrc = hbuf + ((s & 1) ? 65536 : 0) + (size_t)team * 16384;
    short* hdst = hbuf + (((s + 1) & 1) ? 65536 : 0) + (size_t)team * 16384;

    // stage team h(s) -> LDS (linear copy of pre-swizzled buffer).
    #pragma unroll
    for (int q = 0; q < 8; ++q) {
      int off = wave * 4096 + q * 512;  // elements
      gload_lds16((const void*)(hsrc + off + lane * 8), (void*)&h_lds[off]);
    }
    // prefetch this step's gx (independent of recurrence)
    short gxr_[4][3];
    #pragma unroll
    for (int r = 0; r < 4; ++r) {
      size_t base = ((size_t)(bteam + bsub + r) * SEQ + s) * G3 + jcol;
      gxr_[r][0] = gx[base];
      gxr_[r][1] = gx[base + 1024];
      gxr_[r][2] = gx[base + 2048];
    }
    asm volatile("s_waitcnt vmcnt(0)" ::: "memory");
    __syncthreads();

    // gh = h @ whh^T for this wave's 3 gate tiles
    f32x4 acc0 = {0.f,0.f,0.f,0.f}, acc1 = {0.f,0.f,0.f,0.f}, acc2 = {0.f,0.f,0.f,0.f};
    #pragma unroll
    for (int ks = 0; ks < 32; ++ks) {
      int k2 = (ks * 32 + (lane >> 4) * 8) * 2;
      bfrag af = *(const bfrag*)(lbase + (k2 ^ xorm));
      acc0 = __builtin_amdgcn_mfma_f32_16x16x32_bf16(af, wfrag[0][ks], acc0, 0, 0, 0);
      acc1 = __builtin_amdgcn_mfma_f32_16x16x32_bf16(af, wfrag[1][ks], acc1, 0, 0, 0);
      acc2 = __builtin_amdgcn_mfma_f32_16x16x32_bf16(af, wfrag[2][ks], acc2, 0, 0, 0);
    }

    // gates (fp32): r,z,n — torch GRU semantics (b_hh inside r*(), b_ih outside)
    #pragma unroll
    for (int r = 0; r < 4; ++r) {
      float ghr = acc0[r] + bhh_r[0];
      float ghz = acc1[r] + bhh_r[1];
      float ghn = acc2[r] + bhh_r[2];
      float rg = fsig(bf2f(gxr_[r][0]) + bih_r[0] + ghr);
      float zg = fsig(bf2f(gxr_[r][1]) + bih_r[1] + ghz);
      float ng = ftanh(bf2f(gxr_[r][2]) + bih_r[2] + rg * ghn);
      float hn = (1.f - zg) * ng + zg * hprev[r];
      hprev[r] = hn;
      hacc[r] += hn;
      int b = bsub + r;
      // COHERENT store: lands at the agent coherence point, not the local
      // XCD's write-back L2 — readers on other XCDs must see this.
      short* dst = (short*)((char*)hdst + (b * 2048 + ((jcol * 2) ^ ((b & 7) << 4))));
      __hip_atomic_store(dst, (short)f2bf(hn), __ATOMIC_RELAXED, __HIP_MEMORY_SCOPE_AGENT);
    }

    // device-scope team barrier (monotonic counter, reset by memset each launch)
    __builtin_amdgcn_fence(__ATOMIC_RELEASE, "agent");   // drain + writeback before arrival
    __syncthreads();
    if (tid == 0) {
      __hip_atomic_fetch_add(mycnt, 1u, __ATOMIC_RELEASE, __HIP_MEMORY_SCOPE_AGENT);
      unsigned tgt = 16u * (unsigned)(s + 1);
      while (__hip_atomic_load(mycnt, __ATOMIC_RELAXED, __HIP_MEMORY_SCOPE_AGENT) < tgt) {
        __builtin_amdgcn_s_sleep(1);
      }
    }
    __syncthreads();
    __builtin_amdgcn_fence(__ATOMIC_ACQUIRE, "agent");   // invalidate L1/L2 before next h read
  }

  #pragma unroll
  for (int r = 0; r < 4; ++r)
    hsum[(size_t)(bteam + bsub + r) * 1024 + jcol] = hacc[r] * (1.0f / 512.0f);
}

// ---------- kernel 3: mean/logv projections (fp32) ----------
__global__ void proj_kernel(const float* __restrict__ hbar,
                            const float* __restrict__ wm, const float* __restrict__ bm,
                            const float* __restrict__ wl, const float* __restrict__ bl,
                            float* __restrict__ out)
{
  int b = blockIdx.x, t = threadIdx.x;  // 128 threads: 0-63 mean, 64-127 logv
  __shared__ float hrow[1024];
  for (int k = t; k < 1024; k += 128) hrow[k] = hbar[(size_t)b * 1024 + k];
  __syncthreads();
  int j = t & 63;
  const float* w = (t < 64) ? (wm + (size_t)j * 1024) : (wl + (size_t)j * 1024);
  float acc = (t < 64) ? bm[j] : bl[j];
  for (int k = 0; k < 1024; k += 4) {
    f32x4 wv = *(const f32x4*)(w + k);
    acc += hrow[k] * wv[0] + hrow[k+1] * wv[1] + hrow[k+2] * wv[2] + hrow[k+3] * wv[3];
  }
  out[(size_t)((t < 64) ? 0 : 4096) + b * 64 + j] = acc;
}

// ---------- launch ----------
extern "C" void kernel_launch(void* const* d_in, const int* in_sizes, int n_in,
                              void* d_out, int out_size, void* d_ws, size_t ws_size,
                              hipStream_t stream) {
  const int*   ids   = (const int*)d_in[0];
  const float* emb   = (const float*)d_in[1];
  const float* w_ih  = (const float*)d_in[2];
  const float* w_hh  = (const float*)d_in[3];
  const float* b_ih  = (const float*)d_in[4];
  const float* b_hh  = (const float*)d_in[5];
  const float* w_mean= (const float*)d_in[6];
  const float* b_mean= (const float*)d_in[7];
  const float* w_logv= (const float*)d_in[8];
  const float* b_logv= (const float*)d_in[9];
  float* out = (float*)d_out;

  char* ws = (char*)d_ws;
  // ws layout
  unsigned int* cnt  = (unsigned int*)(ws);                 //      1024 B (4 counters, 256B apart)
  short* hbuf        = (short*)(ws + 1024);                 //    262144 B  [2][4][16][1024] bf16
  float* hsum        = (float*)(ws + 1024 + 262144);        //    262144 B  [64][1024] f32
  short* wihb        = (short*)(ws + 1024 + 262144 + 262144);          //   3145728 B
  short* gxbuf       = (short*)(ws + 1024 + 262144 + 262144 + 3145728);// 201326592 B

  // zero counters + h double-buffers + hsum (deterministic across graph replays)
  hipMemsetAsync(ws, 0, 1024 + 262144 + 262144, stream);

  // 0: w_ih -> bf16
  cvt_wih_kernel<<<768, 256, 0, stream>>>(w_ih, wihb);
  // 1: gx GEMM
  gemm_gx_kernel<<<dim3(24, 256), 256, 0, stream>>>(ids, emb, wihb, gxbuf);
  // 2: persistent scan — PLAIN launch. 64 blocks, __launch_bounds__(256,1):
  //    at most 1 block/CU by VGPR budget, 64 <= 256 CUs, sole kernel on the
  //    stream => all blocks co-resident; counter barrier does the grid sync.
  gru_scan_kernel<<<64, 256, 0, stream>>>(gxbuf, w_hh, b_ih, b_hh, hbuf, cnt, hsum);
  // 3: projections
  proj_kernel<<<64, 128, 0, stream>>>(hsum, w_mean, b_mean, w_logv, b_logv, out);
}

// Round 4
// 3493.225 us; speedup vs baseline: 1.1364x; 1.1364x over previous
//
#include <hip/hip_runtime.h>
#include <hip/hip_bf16.h>
#include <stdint.h>
#include <stddef.h>

// Problem sizes (fixed)
#define HID   1024
#define NB    64
#define SEQ   512
#define G3    3072   // 3*HID
#define EMB   512
#define LAT   64

typedef __attribute__((ext_vector_type(4))) float f32x4;
typedef __attribute__((ext_vector_type(8))) short bfrag;  // 8 bf16 (4 VGPRs)

// ---------- helpers ----------
__device__ __forceinline__ unsigned short f2bf(float x) {   // RNE f32->bf16
  union { float f; unsigned u; } v; v.f = x;
  unsigned u = v.u + 0x7fffu + ((v.u >> 16) & 1u);
  return (unsigned short)(u >> 16);
}
__device__ __forceinline__ float bf2f(short s) {
  union { unsigned u; float f; } v; v.u = ((unsigned)(unsigned short)s) << 16;
  return v.f;
}
__device__ __forceinline__ float fsig(float x) {
  return 1.0f / (1.0f + __builtin_exp2f(-1.4426950408889634f * x));
}
__device__ __forceinline__ float ftanh(float x) {
  return 1.0f - 2.0f / (1.0f + __builtin_exp2f(2.8853900817779268f * x));
}
__device__ __forceinline__ void gload_lds16(const void* g, void* l) {
  __builtin_amdgcn_global_load_lds(
      (const __attribute__((address_space(1))) unsigned int*)g,
      (__attribute__((address_space(3))) unsigned int*)l, 16, 0, 0);
}

// ---------- kernel 0: w_ih f32 -> bf16 ----------
__global__ void cvt_wih_kernel(const float* __restrict__ in, short* __restrict__ out) {
  int i = (blockIdx.x * 256 + threadIdx.x) * 8;   // grid sized exactly
  f32x4 a = *(const f32x4*)(in + i);
  f32x4 b = *(const f32x4*)(in + i + 4);
  bfrag o;
  o[0]=(short)f2bf(a[0]); o[1]=(short)f2bf(a[1]); o[2]=(short)f2bf(a[2]); o[3]=(short)f2bf(a[3]);
  o[4]=(short)f2bf(b[0]); o[5]=(short)f2bf(b[1]); o[6]=(short)f2bf(b[2]); o[7]=(short)f2bf(b[3]);
  *(bfrag*)(out + i) = o;
}

// ---------- kernel 1: gx = emb[ids] @ w_ih^T  (bf16 MFMA, fp32 acc, bf16 out) ----------
// grid (24, 256): x = n-tile (3072/128), y = m-tile (32768/128). 256 threads (4 waves 2x2).
__global__ void __launch_bounds__(256) gemm_gx_kernel(
    const int* __restrict__ ids, const float* __restrict__ emb,
    const short* __restrict__ wih, short* __restrict__ gx)
{
  const int nt = blockIdx.x, mt = blockIdx.y;
  const int tid = threadIdx.x;
  const int lane = tid & 63, wave = tid >> 6;
  const int wr = wave >> 1, wc = wave & 1;

  __shared__ __align__(16) short A_lds[128 * 48];  // padded to 48 (16B-aligned rows)
  __shared__ __align__(16) short B_lds[128 * 32];
  __shared__ int ids_s[128];

  if (tid < 128) ids_s[tid] = ids[mt * 128 + tid];
  __syncthreads();

  f32x4 acc[4][4];
  #pragma unroll
  for (int i = 0; i < 4; ++i)
    #pragma unroll
    for (int j = 0; j < 4; ++j) acc[i][j] = (f32x4){0.f, 0.f, 0.f, 0.f};

  const int r_stage = tid >> 1;
  const int kh = (tid & 1) * 16;

  #pragma unroll 1
  for (int kc = 0; kc < 16; ++kc) {
    __syncthreads();   // protect LDS reuse
    // A stage: gather emb rows, cvt f32->bf16, ds_write
    {
      const float* src = emb + (size_t)ids_s[r_stage] * 512 + kc * 32 + kh;
      f32x4 v0 = *(const f32x4*)(src);
      f32x4 v1 = *(const f32x4*)(src + 4);
      f32x4 v2 = *(const f32x4*)(src + 8);
      f32x4 v3 = *(const f32x4*)(src + 12);
      bfrag p0, p1;
      p0[0]=(short)f2bf(v0[0]); p0[1]=(short)f2bf(v0[1]); p0[2]=(short)f2bf(v0[2]); p0[3]=(short)f2bf(v0[3]);
      p0[4]=(short)f2bf(v1[0]); p0[5]=(short)f2bf(v1[1]); p0[6]=(short)f2bf(v1[2]); p0[7]=(short)f2bf(v1[3]);
      p1[0]=(short)f2bf(v2[0]); p1[1]=(short)f2bf(v2[1]); p1[2]=(short)f2bf(v2[2]); p1[3]=(short)f2bf(v2[3]);
      p1[4]=(short)f2bf(v3[0]); p1[5]=(short)f2bf(v3[1]); p1[6]=(short)f2bf(v3[2]); p1[7]=(short)f2bf(v3[3]);
      *(bfrag*)&A_lds[r_stage * 48 + kh]     = p0;
      *(bfrag*)&A_lds[r_stage * 48 + kh + 8] = p1;
    }
    // B stage: direct global->LDS (bf16 already), 2 instrs per wave
    {
      #pragma unroll
      for (int ii = 0; ii < 2; ++ii) {
        int i = wave * 2 + ii;
        const short* src = wih + (size_t)(nt * 128 + i * 16 + (lane >> 2)) * 512
                               + kc * 32 + (lane & 3) * 8;
        gload_lds16((const void*)src, (void*)&B_lds[i * 512]);
      }
    }
    asm volatile("s_waitcnt vmcnt(0)" ::: "memory");
    __syncthreads();

    bfrag a[4], b[4];
    #pragma unroll
    for (int mi = 0; mi < 4; ++mi)
      a[mi] = *(const bfrag*)&A_lds[(wr * 64 + mi * 16 + (lane & 15)) * 48 + (lane >> 4) * 8];
    #pragma unroll
    for (int ni = 0; ni < 4; ++ni)
      b[ni] = *(const bfrag*)&B_lds[(wc * 64 + ni * 16 + (lane & 15)) * 32 + (lane >> 4) * 8];
    #pragma unroll
    for (int mi = 0; mi < 4; ++mi)
      #pragma unroll
      for (int ni = 0; ni < 4; ++ni)
        acc[mi][ni] = __builtin_amdgcn_mfma_f32_16x16x32_bf16(a[mi], b[ni], acc[mi][ni], 0, 0, 0);
  }

  // epilogue: store bf16 gx[m][n]
  #pragma unroll
  for (int mi = 0; mi < 4; ++mi)
    #pragma unroll
    for (int ni = 0; ni < 4; ++ni)
      #pragma unroll
      for (int r = 0; r < 4; ++r) {
        int m = mt * 128 + wr * 64 + mi * 16 + (lane >> 4) * 4 + r;
        int n = nt * 128 + wc * 64 + ni * 16 + (lane & 15);
        gx[(size_t)m * G3 + n] = (short)f2bf(acc[mi][ni][r]);
      }
}

// ---------- kernel 2: persistent GRU scan (PLAIN launch, 64 WGs <= 256 CUs) ----------
// team = blockIdx>>4 owns 16 batch rows; each wave owns 16 hidden cols x 3 gates
// (w_hh slice in ~384 VGPRs). NO cache-wide fences: the only cross-WG data
// (hbuf, cnt) is accessed exclusively with agent-scope atomic ops (sc0/sc1 =
// write-through / L1-L2-bypass reads), so gx/L2 state survives across steps.
__global__ void __launch_bounds__(256, 1) gru_scan_kernel(
    const short* __restrict__ gx, const float* __restrict__ whh,
    const float* __restrict__ bihp, const float* __restrict__ bhhp,
    short* __restrict__ hbuf, unsigned int* __restrict__ cnt,
    float* __restrict__ hsum)
{
  const int team = blockIdx.x >> 4;
  const int wgi  = blockIdx.x & 15;
  const int tid  = threadIdx.x;
  const int lane = tid & 63, wave = tid >> 6;
  const int jcol = (wgi * 4 + wave) * 16 + (lane & 15);  // hidden col this lane owns
  const int bsub = (lane >> 4) * 4;                      // local batch-row base (C/D rows)
  const int bteam = team * 16;

  __shared__ __align__(16) short h_lds[16 * 1024];       // 32 KB, swizzled layout

  // --- load w_hh slice into registers as B-fragments (bf16) ---
  bfrag wfrag[3][32];
  #pragma unroll
  for (int g = 0; g < 3; ++g) {
    const float* wrow = whh + (size_t)(g * 1024 + jcol) * 1024 + (lane >> 4) * 8;
    #pragma unroll
    for (int ks = 0; ks < 32; ++ks) {
      const float* p = wrow + ks * 32;
      f32x4 lo = *(const f32x4*)p;
      f32x4 hi = *(const f32x4*)(p + 4);
      bfrag f;
      f[0]=(short)f2bf(lo[0]); f[1]=(short)f2bf(lo[1]); f[2]=(short)f2bf(lo[2]); f[3]=(short)f2bf(lo[3]);
      f[4]=(short)f2bf(hi[0]); f[5]=(short)f2bf(hi[1]); f[6]=(short)f2bf(hi[2]); f[7]=(short)f2bf(hi[3]);
      wfrag[g][ks] = f;
    }
  }
  float bih_r[3], bhh_r[3];
  #pragma unroll
  for (int g = 0; g < 3; ++g) {
    bih_r[g] = bihp[g * 1024 + jcol];
    bhh_r[g] = bhhp[g * 1024 + jcol];
  }

  float hprev[4] = {0.f, 0.f, 0.f, 0.f};
  float hacc[4]  = {0.f, 0.f, 0.f, 0.f};
  unsigned int* mycnt = cnt + team * 64;   // 256B-separated counters
  const int bl = lane & 15;
  const int xorm = (bl & 7) << 4;
  const char* lbase = (const char*)h_lds + bl * 2048;

  // gx prefetch registers for the CURRENT step (loaded one barrier early)
  short gxr_[4][3];
  #pragma unroll
  for (int r = 0; r < 4; ++r) {
    size_t base = ((size_t)(bteam + bsub + r) * SEQ + 0) * G3 + jcol;
    gxr_[r][0] = gx[base];
    gxr_[r][1] = gx[base + 1024];
    gxr_[r][2] = gx[base + 2048];
  }

  #pragma unroll 1
  for (int s = 0; s < SEQ; ++s) {
    const short* hsrc = hbuf + ((s & 1) ? 65536 : 0) + (size_t)team * 16384;
    short* hdst = hbuf + (((s + 1) & 1) ? 65536 : 0) + (size_t)team * 16384;

    // stage team h(s) -> LDS via agent-scope 8B atomic loads (bypass stale
    // L1/L2, fetch from coherence point) + ds_write. 128 B per thread.
    {
      const unsigned long long* gsrc =
          (const unsigned long long*)((const char*)hsrc + tid * 128);
      unsigned long long hv[16];
      #pragma unroll
      for (int q = 0; q < 16; ++q)
        hv[q] = __hip_atomic_load(gsrc + q, __ATOMIC_RELAXED, __HIP_MEMORY_SCOPE_AGENT);
      unsigned long long* ldst = (unsigned long long*)((char*)h_lds + tid * 128);
      #pragma unroll
      for (int q = 0; q < 16; ++q) ldst[q] = hv[q];
    }
    __syncthreads();

    // gh = h @ whh^T for this wave's 3 gate tiles
    f32x4 acc0 = {0.f,0.f,0.f,0.f}, acc1 = {0.f,0.f,0.f,0.f}, acc2 = {0.f,0.f,0.f,0.f};
    #pragma unroll
    for (int ks = 0; ks < 32; ++ks) {
      int k2 = (ks * 32 + (lane >> 4) * 8) * 2;
      bfrag af = *(const bfrag*)(lbase + (k2 ^ xorm));
      acc0 = __builtin_amdgcn_mfma_f32_16x16x32_bf16(af, wfrag[0][ks], acc0, 0, 0, 0);
      acc1 = __builtin_amdgcn_mfma_f32_16x16x32_bf16(af, wfrag[1][ks], acc1, 0, 0, 0);
      acc2 = __builtin_amdgcn_mfma_f32_16x16x32_bf16(af, wfrag[2][ks], acc2, 0, 0, 0);
    }

    // gates (fp32): r,z,n — torch GRU semantics (b_hh inside r*(), b_ih outside)
    #pragma unroll
    for (int r = 0; r < 4; ++r) {
      float ghr = acc0[r] + bhh_r[0];
      float ghz = acc1[r] + bhh_r[1];
      float ghn = acc2[r] + bhh_r[2];
      float rg = fsig(bf2f(gxr_[r][0]) + bih_r[0] + ghr);
      float zg = fsig(bf2f(gxr_[r][1]) + bih_r[1] + ghz);
      float ng = ftanh(bf2f(gxr_[r][2]) + bih_r[2] + rg * ghn);
      float hn = (1.f - zg) * ng + zg * hprev[r];
      hprev[r] = hn;
      hacc[r] += hn;
      int b = bsub + r;
      // agent-scope write-through store: lands at the coherence point.
      short* dst = (short*)((char*)hdst + (b * 2048 + ((jcol * 2) ^ ((b & 7) << 4))));
      __hip_atomic_store(dst, (short)f2bf(hn), __ATOMIC_RELAXED, __HIP_MEMORY_SCOPE_AGENT);
    }

    // drain h stores to coherence point (no cache-wide writeback needed:
    // stores are already write-through), then team barrier.
    asm volatile("s_waitcnt vmcnt(0)" ::: "memory");
    __syncthreads();

    // prefetch next step's gx while the barrier settles (recurrence-independent)
    {
      int sn = (s + 1 < SEQ) ? (s + 1) : s;
      #pragma unroll
      for (int r = 0; r < 4; ++r) {
        size_t base = ((size_t)(bteam + bsub + r) * SEQ + sn) * G3 + jcol;
        gxr_[r][0] = gx[base];
        gxr_[r][1] = gx[base + 1024];
        gxr_[r][2] = gx[base + 2048];
      }
    }

    if (tid == 0) {
      __hip_atomic_fetch_add(mycnt, 1u, __ATOMIC_RELAXED, __HIP_MEMORY_SCOPE_AGENT);
      unsigned tgt = 16u * (unsigned)(s + 1);
      while (__hip_atomic_load(mycnt, __ATOMIC_RELAXED, __HIP_MEMORY_SCOPE_AGENT) < tgt) {
        __builtin_amdgcn_s_sleep(1);
      }
    }
    __syncthreads();
  }

  #pragma unroll
  for (int r = 0; r < 4; ++r)
    hsum[(size_t)(bteam + bsub + r) * 1024 + jcol] = hacc[r] * (1.0f / 512.0f);
}

// ---------- kernel 3: mean/logv projections (fp32) ----------
__global__ void proj_kernel(const float* __restrict__ hbar,
                            const float* __restrict__ wm, const float* __restrict__ bm,
                            const float* __restrict__ wl, const float* __restrict__ bl,
                            float* __restrict__ out)
{
  int b = blockIdx.x, t = threadIdx.x;  // 128 threads: 0-63 mean, 64-127 logv
  __shared__ float hrow[1024];
  for (int k = t; k < 1024; k += 128) hrow[k] = hbar[(size_t)b * 1024 + k];
  __syncthreads();
  int j = t & 63;
  const float* w = (t < 64) ? (wm + (size_t)j * 1024) : (wl + (size_t)j * 1024);
  float acc = (t < 64) ? bm[j] : bl[j];
  for (int k = 0; k < 1024; k += 4) {
    f32x4 wv = *(const f32x4*)(w + k);
    acc += hrow[k] * wv[0] + hrow[k+1] * wv[1] + hrow[k+2] * wv[2] + hrow[k+3] * wv[3];
  }
  out[(size_t)((t < 64) ? 0 : 4096) + b * 64 + j] = acc;
}

// ---------- launch ----------
extern "C" void kernel_launch(void* const* d_in, const int* in_sizes, int n_in,
                              void* d_out, int out_size, void* d_ws, size_t ws_size,
                              hipStream_t stream) {
  const int*   ids   = (const int*)d_in[0];
  const float* emb   = (const float*)d_in[1];
  const float* w_ih  = (const float*)d_in[2];
  const float* w_hh  = (const float*)d_in[3];
  const float* b_ih  = (const float*)d_in[4];
  const float* b_hh  = (const float*)d_in[5];
  const float* w_mean= (const float*)d_in[6];
  const float* b_mean= (const float*)d_in[7];
  const float* w_logv= (const float*)d_in[8];
  const float* b_logv= (const float*)d_in[9];
  float* out = (float*)d_out;

  char* ws = (char*)d_ws;
  // ws layout
  unsigned int* cnt  = (unsigned int*)(ws);                 //      1024 B (4 counters, 256B apart)
  short* hbuf        = (short*)(ws + 1024);                 //    262144 B  [2][4][16][1024] bf16
  float* hsum        = (float*)(ws + 1024 + 262144);        //    262144 B  [64][1024] f32
  short* wihb        = (short*)(ws + 1024 + 262144 + 262144);          //   3145728 B
  short* gxbuf       = (short*)(ws + 1024 + 262144 + 262144 + 3145728);// 201326592 B

  // zero counters + h double-buffers + hsum (deterministic across graph replays)
  hipMemsetAsync(ws, 0, 1024 + 262144 + 262144, stream);

  // 0: w_ih -> bf16
  cvt_wih_kernel<<<768, 256, 0, stream>>>(w_ih, wihb);
  // 1: gx GEMM
  gemm_gx_kernel<<<dim3(24, 256), 256, 0, stream>>>(ids, emb, wihb, gxbuf);
  // 2: persistent scan — PLAIN launch. 64 blocks, __launch_bounds__(256,1):
  //    at most 1 block/CU by VGPR budget, 64 <= 256 CUs, sole kernel on the
  //    stream => all blocks co-resident; counter barrier does the grid sync.
  gru_scan_kernel<<<64, 256, 0, stream>>>(gxbuf, w_hh, b_ih, b_hh, hbuf, cnt, hsum);
  // 3: projections
  proj_kernel<<<64, 128, 0, stream>>>(hsum, w_mean, b_mean, w_logv, b_logv, out);
}

// Round 5
// 2572.154 us; speedup vs baseline: 1.5433x; 1.3581x over previous
//
#include <hip/hip_runtime.h>
#include <hip/hip_bf16.h>
#include <stdint.h>
#include <stddef.h>

// Problem sizes (fixed)
#define HID   1024
#define NB    64
#define SEQ   512
#define G3    3072   // 3*HID
#define EMB   512
#define LAT   64

typedef __attribute__((ext_vector_type(4))) float f32x4;
typedef __attribute__((ext_vector_type(8))) short bfrag;  // 8 bf16 (4 VGPRs)

// ---------- helpers ----------
__device__ __forceinline__ unsigned short f2bf(float x) {   // RNE f32->bf16
  union { float f; unsigned u; } v; v.f = x;
  unsigned u = v.u + 0x7fffu + ((v.u >> 16) & 1u);
  return (unsigned short)(u >> 16);
}
__device__ __forceinline__ float bf2f(short s) {
  union { unsigned u; float f; } v; v.u = ((unsigned)(unsigned short)s) << 16;
  return v.f;
}
__device__ __forceinline__ float fsig(float x) {
  return 1.0f / (1.0f + __builtin_exp2f(-1.4426950408889634f * x));
}
__device__ __forceinline__ float ftanh(float x) {
  return 1.0f - 2.0f / (1.0f + __builtin_exp2f(2.8853900817779268f * x));
}
__device__ __forceinline__ void gload_lds16(const void* g, void* l) {
  __builtin_amdgcn_global_load_lds(
      (const __attribute__((address_space(1))) unsigned int*)g,
      (__attribute__((address_space(3))) unsigned int*)l, 16, 0, 0);
}

// ---------- kernel 0: w_ih f32 -> bf16 ----------
__global__ void cvt_wih_kernel(const float* __restrict__ in, short* __restrict__ out) {
  int i = (blockIdx.x * 256 + threadIdx.x) * 8;   // grid sized exactly
  f32x4 a = *(const f32x4*)(in + i);
  f32x4 b = *(const f32x4*)(in + i + 4);
  bfrag o;
  o[0]=(short)f2bf(a[0]); o[1]=(short)f2bf(a[1]); o[2]=(short)f2bf(a[2]); o[3]=(short)f2bf(a[3]);
  o[4]=(short)f2bf(b[0]); o[5]=(short)f2bf(b[1]); o[6]=(short)f2bf(b[2]); o[7]=(short)f2bf(b[3]);
  *(bfrag*)(out + i) = o;
}

// ---------- kernel 1: gx = emb[ids] @ w_ih^T  (bf16 MFMA, fp32 acc, bf16 out) ----------
// grid (24, 256): x = n-tile (3072/128), y = m-tile (32768/128). 256 threads (4 waves 2x2).
__global__ void __launch_bounds__(256) gemm_gx_kernel(
    const int* __restrict__ ids, const float* __restrict__ emb,
    const short* __restrict__ wih, short* __restrict__ gx)
{
  const int nt = blockIdx.x, mt = blockIdx.y;
  const int tid = threadIdx.x;
  const int lane = tid & 63, wave = tid >> 6;
  const int wr = wave >> 1, wc = wave & 1;

  __shared__ __align__(16) short A_lds[128 * 48];  // padded to 48 (16B-aligned rows)
  __shared__ __align__(16) short B_lds[128 * 32];
  __shared__ int ids_s[128];

  if (tid < 128) ids_s[tid] = ids[mt * 128 + tid];
  __syncthreads();

  f32x4 acc[4][4];
  #pragma unroll
  for (int i = 0; i < 4; ++i)
    #pragma unroll
    for (int j = 0; j < 4; ++j) acc[i][j] = (f32x4){0.f, 0.f, 0.f, 0.f};

  const int r_stage = tid >> 1;
  const int kh = (tid & 1) * 16;

  #pragma unroll 1
  for (int kc = 0; kc < 16; ++kc) {
    __syncthreads();   // protect LDS reuse
    // A stage: gather emb rows, cvt f32->bf16, ds_write
    {
      const float* src = emb + (size_t)ids_s[r_stage] * 512 + kc * 32 + kh;
      f32x4 v0 = *(const f32x4*)(src);
      f32x4 v1 = *(const f32x4*)(src + 4);
      f32x4 v2 = *(const f32x4*)(src + 8);
      f32x4 v3 = *(const f32x4*)(src + 12);
      bfrag p0, p1;
      p0[0]=(short)f2bf(v0[0]); p0[1]=(short)f2bf(v0[1]); p0[2]=(short)f2bf(v0[2]); p0[3]=(short)f2bf(v0[3]);
      p0[4]=(short)f2bf(v1[0]); p0[5]=(short)f2bf(v1[1]); p0[6]=(short)f2bf(v1[2]); p0[7]=(short)f2bf(v1[3]);
      p1[0]=(short)f2bf(v2[0]); p1[1]=(short)f2bf(v2[1]); p1[2]=(short)f2bf(v2[2]); p1[3]=(short)f2bf(v2[3]);
      p1[4]=(short)f2bf(v3[0]); p1[5]=(short)f2bf(v3[1]); p1[6]=(short)f2bf(v3[2]); p1[7]=(short)f2bf(v3[3]);
      *(bfrag*)&A_lds[r_stage * 48 + kh]     = p0;
      *(bfrag*)&A_lds[r_stage * 48 + kh + 8] = p1;
    }
    // B stage: direct global->LDS (bf16 already), 2 instrs per wave
    {
      #pragma unroll
      for (int ii = 0; ii < 2; ++ii) {
        int i = wave * 2 + ii;
        const short* src = wih + (size_t)(nt * 128 + i * 16 + (lane >> 2)) * 512
                               + kc * 32 + (lane & 3) * 8;
        gload_lds16((const void*)src, (void*)&B_lds[i * 512]);
      }
    }
    asm volatile("s_waitcnt vmcnt(0)" ::: "memory");
    __syncthreads();

    bfrag a[4], b[4];
    #pragma unroll
    for (int mi = 0; mi < 4; ++mi)
      a[mi] = *(const bfrag*)&A_lds[(wr * 64 + mi * 16 + (lane & 15)) * 48 + (lane >> 4) * 8];
    #pragma unroll
    for (int ni = 0; ni < 4; ++ni)
      b[ni] = *(const bfrag*)&B_lds[(wc * 64 + ni * 16 + (lane & 15)) * 32 + (lane >> 4) * 8];
    #pragma unroll
    for (int mi = 0; mi < 4; ++mi)
      #pragma unroll
      for (int ni = 0; ni < 4; ++ni)
        acc[mi][ni] = __builtin_amdgcn_mfma_f32_16x16x32_bf16(a[mi], b[ni], acc[mi][ni], 0, 0, 0);
  }

  // epilogue: store bf16 gx[m][n]
  #pragma unroll
  for (int mi = 0; mi < 4; ++mi)
    #pragma unroll
    for (int ni = 0; ni < 4; ++ni)
      #pragma unroll
      for (int r = 0; r < 4; ++r) {
        int m = mt * 128 + wr * 64 + mi * 16 + (lane >> 4) * 4 + r;
        int n = nt * 128 + wc * 64 + ni * 16 + (lane & 15);
        gx[(size_t)m * G3 + n] = (short)f2bf(acc[mi][ni][r]);
      }
}

// ---------- kernel 2: persistent GRU scan (PLAIN launch, 64 WGs <= 256 CUs) ----------
// team = blockIdx>>4 owns 16 batch rows; each wave owns 16 hidden cols x 3 gates.
// Per step: stage team h (32KB) to LDS via COALESCED agent-scope 8B loads
// (qword index q*256+tid: 512B contiguous per wave-instruction, 2-way LDS banks),
// 96 MFMAs/wave, gates in fp32, agent-scope write-through h stores, counter barrier.
__global__ void __launch_bounds__(256, 1) gru_scan_kernel(
    const short* __restrict__ gx, const float* __restrict__ whh,
    const float* __restrict__ bihp, const float* __restrict__ bhhp,
    short* __restrict__ hbuf, unsigned int* __restrict__ cnt,
    float* __restrict__ hsum)
{
  const int team = blockIdx.x >> 4;
  const int wgi  = blockIdx.x & 15;
  const int tid  = threadIdx.x;
  const int lane = tid & 63, wave = tid >> 6;
  const int jcol = (wgi * 4 + wave) * 16 + (lane & 15);  // hidden col this lane owns
  const int bsub = (lane >> 4) * 4;                      // local batch-row base (C/D rows)
  const int bteam = team * 16;

  __shared__ __align__(16) short h_lds[16 * 1024];       // 32 KB, swizzled layout

  // --- load w_hh slice into registers as B-fragments (bf16) ---
  bfrag wfrag[3][32];
  #pragma unroll
  for (int g = 0; g < 3; ++g) {
    const float* wrow = whh + (size_t)(g * 1024 + jcol) * 1024 + (lane >> 4) * 8;
    #pragma unroll
    for (int ks = 0; ks < 32; ++ks) {
      const float* p = wrow + ks * 32;
      f32x4 lo = *(const f32x4*)p;
      f32x4 hi = *(const f32x4*)(p + 4);
      bfrag f;
      f[0]=(short)f2bf(lo[0]); f[1]=(short)f2bf(lo[1]); f[2]=(short)f2bf(lo[2]); f[3]=(short)f2bf(lo[3]);
      f[4]=(short)f2bf(hi[0]); f[5]=(short)f2bf(hi[1]); f[6]=(short)f2bf(hi[2]); f[7]=(short)f2bf(hi[3]);
      wfrag[g][ks] = f;
    }
  }
  float bih_r[3], bhh_r[3];
  #pragma unroll
  for (int g = 0; g < 3; ++g) {
    bih_r[g] = bihp[g * 1024 + jcol];
    bhh_r[g] = bhhp[g * 1024 + jcol];
  }

  float hprev[4] = {0.f, 0.f, 0.f, 0.f};
  float hacc[4]  = {0.f, 0.f, 0.f, 0.f};
  unsigned int* mycnt = cnt + team * 64;   // 256B-separated counters
  const int bl = lane & 15;
  const int xorm = (bl & 7) << 4;
  const char* lbase = (const char*)h_lds + bl * 2048;

  // gx prefetch registers for the CURRENT step (loaded one barrier early)
  short gxr_[4][3];
  #pragma unroll
  for (int r = 0; r < 4; ++r) {
    size_t base = ((size_t)(bteam + bsub + r) * SEQ + 0) * G3 + jcol;
    gxr_[r][0] = gx[base];
    gxr_[r][1] = gx[base + 1024];
    gxr_[r][2] = gx[base + 2048];
  }

  #pragma unroll 1
  for (int s = 0; s < SEQ; ++s) {
    const short* hsrc = hbuf + ((s & 1) ? 65536 : 0) + (size_t)team * 16384;
    short* hdst = hbuf + (((s + 1) & 1) ? 65536 : 0) + (size_t)team * 16384;

    // stage team h(s) -> LDS via agent-scope 8B atomic loads, COALESCED:
    // qword index q*256 + tid => per wave-instruction lanes cover a contiguous
    // 512B burst; ds_write lane stride 8B => 2-way banks (free).
    {
      const unsigned long long* gsrc = (const unsigned long long*)hsrc;  // 4096 qwords
      unsigned long long* ldst = (unsigned long long*)h_lds;
      unsigned long long hv[16];
      #pragma unroll
      for (int q = 0; q < 16; ++q)
        hv[q] = __hip_atomic_load(gsrc + q * 256 + tid, __ATOMIC_RELAXED,
                                  __HIP_MEMORY_SCOPE_AGENT);
      #pragma unroll
      for (int q = 0; q < 16; ++q) ldst[q * 256 + tid] = hv[q];
    }
    __syncthreads();

    // gh = h @ whh^T for this wave's 3 gate tiles
    f32x4 acc0 = {0.f,0.f,0.f,0.f}, acc1 = {0.f,0.f,0.f,0.f}, acc2 = {0.f,0.f,0.f,0.f};
    #pragma unroll
    for (int ks = 0; ks < 32; ++ks) {
      int k2 = (ks * 32 + (lane >> 4) * 8) * 2;
      bfrag af = *(const bfrag*)(lbase + (k2 ^ xorm));
      acc0 = __builtin_amdgcn_mfma_f32_16x16x32_bf16(af, wfrag[0][ks], acc0, 0, 0, 0);
      acc1 = __builtin_amdgcn_mfma_f32_16x16x32_bf16(af, wfrag[1][ks], acc1, 0, 0, 0);
      acc2 = __builtin_amdgcn_mfma_f32_16x16x32_bf16(af, wfrag[2][ks], acc2, 0, 0, 0);
    }

    // gates (fp32): r,z,n — torch GRU semantics (b_hh inside r*(), b_ih outside)
    #pragma unroll
    for (int r = 0; r < 4; ++r) {
      float ghr = acc0[r] + bhh_r[0];
      float ghz = acc1[r] + bhh_r[1];
      float ghn = acc2[r] + bhh_r[2];
      float rg = fsig(bf2f(gxr_[r][0]) + bih_r[0] + ghr);
      float zg = fsig(bf2f(gxr_[r][1]) + bih_r[1] + ghz);
      float ng = ftanh(bf2f(gxr_[r][2]) + bih_r[2] + rg * ghn);
      float hn = (1.f - zg) * ng + zg * hprev[r];
      hprev[r] = hn;
      hacc[r] += hn;
      int b = bsub + r;
      // agent-scope write-through store: lands at the coherence point.
      short* dst = (short*)((char*)hdst + (b * 2048 + ((jcol * 2) ^ ((b & 7) << 4))));
      __hip_atomic_store(dst, (short)f2bf(hn), __ATOMIC_RELAXED, __HIP_MEMORY_SCOPE_AGENT);
    }

    // drain h stores to coherence point, then team barrier.
    asm volatile("s_waitcnt vmcnt(0)" ::: "memory");
    __syncthreads();

    // prefetch next step's gx while the barrier settles (recurrence-independent)
    {
      int sn = (s + 1 < SEQ) ? (s + 1) : s;
      #pragma unroll
      for (int r = 0; r < 4; ++r) {
        size_t base = ((size_t)(bteam + bsub + r) * SEQ + sn) * G3 + jcol;
        gxr_[r][0] = gx[base];
        gxr_[r][1] = gx[base + 1024];
        gxr_[r][2] = gx[base + 2048];
      }
    }

    if (tid == 0) {
      __hip_atomic_fetch_add(mycnt, 1u, __ATOMIC_RELAXED, __HIP_MEMORY_SCOPE_AGENT);
      unsigned tgt = 16u * (unsigned)(s + 1);
      // tight poll: agent-scope load latency (~700cy) is the natural interval
      while (__hip_atomic_load(mycnt, __ATOMIC_RELAXED, __HIP_MEMORY_SCOPE_AGENT) < tgt) { }
    }
    __syncthreads();
  }

  #pragma unroll
  for (int r = 0; r < 4; ++r)
    hsum[(size_t)(bteam + bsub + r) * 1024 + jcol] = hacc[r] * (1.0f / 512.0f);
}

// ---------- kernel 3: mean/logv projections (fp32) ----------
__global__ void proj_kernel(const float* __restrict__ hbar,
                            const float* __restrict__ wm, const float* __restrict__ bm,
                            const float* __restrict__ wl, const float* __restrict__ bl,
                            float* __restrict__ out)
{
  int b = blockIdx.x, t = threadIdx.x;  // 128 threads: 0-63 mean, 64-127 logv
  __shared__ float hrow[1024];
  for (int k = t; k < 1024; k += 128) hrow[k] = hbar[(size_t)b * 1024 + k];
  __syncthreads();
  int j = t & 63;
  const float* w = (t < 64) ? (wm + (size_t)j * 1024) : (wl + (size_t)j * 1024);
  float acc = (t < 64) ? bm[j] : bl[j];
  for (int k = 0; k < 1024; k += 4) {
    f32x4 wv = *(const f32x4*)(w + k);
    acc += hrow[k] * wv[0] + hrow[k+1] * wv[1] + hrow[k+2] * wv[2] + hrow[k+3] * wv[3];
  }
  out[(size_t)((t < 64) ? 0 : 4096) + b * 64 + j] = acc;
}

// ---------- launch ----------
extern "C" void kernel_launch(void* const* d_in, const int* in_sizes, int n_in,
                              void* d_out, int out_size, void* d_ws, size_t ws_size,
                              hipStream_t stream) {
  const int*   ids   = (const int*)d_in[0];
  const float* emb   = (const float*)d_in[1];
  const float* w_ih  = (const float*)d_in[2];
  const float* w_hh  = (const float*)d_in[3];
  const float* b_ih  = (const float*)d_in[4];
  const float* b_hh  = (const float*)d_in[5];
  const float* w_mean= (const float*)d_in[6];
  const float* b_mean= (const float*)d_in[7];
  const float* w_logv= (const float*)d_in[8];
  const float* b_logv= (const float*)d_in[9];
  float* out = (float*)d_out;

  char* ws = (char*)d_ws;
  // ws layout
  unsigned int* cnt  = (unsigned int*)(ws);                 //      1024 B (4 counters, 256B apart)
  short* hbuf        = (short*)(ws + 1024);                 //    262144 B  [2][4][16][1024] bf16
  float* hsum        = (float*)(ws + 1024 + 262144);        //    262144 B  [64][1024] f32
  short* wihb        = (short*)(ws + 1024 + 262144 + 262144);          //   3145728 B
  short* gxbuf       = (short*)(ws + 1024 + 262144 + 262144 + 3145728);// 201326592 B

  // zero counters + h double-buffers + hsum (deterministic across graph replays)
  hipMemsetAsync(ws, 0, 1024 + 262144 + 262144, stream);

  // 0: w_ih -> bf16
  cvt_wih_kernel<<<768, 256, 0, stream>>>(w_ih, wihb);
  // 1: gx GEMM
  gemm_gx_kernel<<<dim3(24, 256), 256, 0, stream>>>(ids, emb, wihb, gxbuf);
  // 2: persistent scan — PLAIN launch. 64 blocks, __launch_bounds__(256,1):
  //    at most 1 block/CU, 64 <= 256 CUs, sole kernel on the stream
  //    => all blocks co-resident; counter barrier does the grid sync.
  gru_scan_kernel<<<64, 256, 0, stream>>>(gxbuf, w_hh, b_ih, b_hh, hbuf, cnt, hsum);
  // 3: projections
  proj_kernel<<<64, 128, 0, stream>>>(hsum, w_mean, b_mean, w_logv, b_logv, out);
}